// Round 5
// baseline (227.135 us; speedup 1.0000x reference)
//
#include <hip/hip_runtime.h>

#define MM 576
#define NBLK 128    // 4n x 4t x 8s, one block per CU on half the chip

__device__ __forceinline__ float lrelu(float x) { return x > 0.f ? x : 0.2f * x; }
__device__ __forceinline__ float elu1(float x)  { return x > 0.f ? x : (__expf(x) - 1.f); }

// Grid barrier: one arrival RMW per block + load-only polling.
// Cross-barrier payload is only the 128KB e-partials (plain coalesced
// stores), so the release wbl2 has almost nothing dirty to write back.
__device__ __forceinline__ void grid_barrier(unsigned* cnt, unsigned target) {
    __syncthreads();
    if (threadIdx.x == 0) {
        __threadfence();
        __hip_atomic_fetch_add(cnt, 1u, __ATOMIC_RELAXED, __HIP_MEMORY_SCOPE_AGENT);
        while (__hip_atomic_load(cnt, __ATOMIC_RELAXED, __HIP_MEMORY_SCOPE_AGENT) < target)
            __builtin_amdgcn_s_sleep(2);
        __threadfence();
    }
    __syncthreads();
}

struct SMem {
    float Wh[4][4][18][32];   // [hd][tt][r][v] 36 KB — block-private, never spilled
    float xb[18][4][32];      // x / inter slice 9 KB — layer boundary lives here
    float e[4][4][2][32];     // [hd][q][which][v] gathered full logits, 4 KB
    float adj[1024];          // adjn scratch (also phase1 red[4][4][2][32])
    float att[1024];          // att scratch
    float C[1024];            // C[j][u] for current (hd,tout)
    float wred[16];
    float d12[32];
};                            // 62656 B static

// ---------------------------------------------------------------------------
// Phase 1: block (n,t,s) owns rows m = t*144 + s*18 + [0,18).
// Loads x slice to LDS (layer 0 only; layer 1 slice already in xb), computes
// Wh for 4 heads x 4 t' into LDS, and publishes e-partials (256 floats,
// one coalesced 1KB store) to epart[n][q=t][s][hd][wh][v].
// ---------------------------------------------------------------------------
__device__ void phase1(int n, int t, int s,
                       const float* __restrict__ xin,
                       const float* __restrict__ mw_l,
                       const float* __restrict__ mb_l,
                       const float* __restrict__ a_l,
                       float* __restrict__ epart,
                       SMem& sm) {
    int tid = threadIdx.x;
    __syncthreads();    // xb/Wh safe to overwrite; prior phase done
    if (xin) {
        const float4* src = (const float4*)(xin + (size_t)(n * MM + t * 144 + s * 18) * 128);
        float4* dst = (float4*)&sm.xb[0][0][0];
        for (int p = tid; p < 576; p += 256) dst[p] = src[p];
        __syncthreads();
    }
    int sub = tid >> 5, v = tid & 31;
    float ei[4] = {0.f, 0.f, 0.f, 0.f}, ej[4] = {0.f, 0.f, 0.f, 0.f};
    for (int r = sub; r < 18; r += 8) {
        int rr = s * 18 + r;
        int dh = rr / 24, wc = rr % 24;
        float x0 = sm.xb[r][0][v], x1 = sm.xb[r][1][v];
        float x2 = sm.xb[r][2][v], x3 = sm.xb[r][3][v];
#pragma unroll
        for (int hd = 0; hd < 4; ++hd) {
            const float* ab = a_l + hd * 1152 + dh * 192 + wc * 4;
            float4 aiv = *(const float4*)ab;
            float4 ajv = *(const float4*)(ab + 96);
#pragma unroll
            for (int tt = 0; tt < 4; ++tt) {
                float wh = fmaf(x0, mw_l[hd * 16 + tt],
                            fmaf(x1, mw_l[hd * 16 + 4 + tt],
                             fmaf(x2, mw_l[hd * 16 + 8 + tt],
                              fmaf(x3, mw_l[hd * 16 + 12 + tt], mb_l[hd * 4 + tt]))));
                sm.Wh[hd][tt][r][v] = wh;
                float ai = (&aiv.x)[tt], aj = (&ajv.x)[tt];
                ei[hd] = fmaf(wh, ai, ei[hd]);
                ej[hd] = fmaf(wh, aj, ej[hd]);
            }
        }
    }
    // fold sub-pairs within each wave, then cross-wave reduce in LDS (red = adj)
    float* red = sm.adj;     // [w][hd][wh][v] = 4*4*2*32
    int w = tid >> 6, half = (tid >> 5) & 1;
#pragma unroll
    for (int hd = 0; hd < 4; ++hd) {
        float eif = ei[hd] + __shfl_xor(ei[hd], 32, 64);
        float ejf = ej[hd] + __shfl_xor(ej[hd], 32, 64);
        red[((w * 4 + hd) * 2 + half) * 32 + v] = half ? ejf : eif;
    }
    __syncthreads();
    {
        int hdx = tid >> 6, whx = (tid >> 5) & 1, vx = tid & 31;
        float e = 0.f;
#pragma unroll
        for (int ww = 0; ww < 4; ++ww)
            e += red[((ww * 4 + hdx) * 2 + whx) * 32 + vx];
        epart[(((size_t)(n * 4 + t) * 8 + s) << 8) + tid] = e;   // tid == hd*64+wh*32+v
    }
}

// ---------------------------------------------------------------------------
// Phase 2+3 (every block, redundant softmax/C per n): gather e-partials,
// then per (hd): adjn; per (hd,tout): att -> C -> GEMM-accumulate
//   acc[r][tout] += elu(sum_j Wh[hd][tout][r][j] * C[j][u])
// Layer 0 writes xb (layer-2 input); layer 1 writes global out.
// ---------------------------------------------------------------------------
__device__ void phase23(int n, int t, int s, int layer,
                        const float* __restrict__ Bp,
                        const float* __restrict__ epart,
                        float* __restrict__ outg,
                        SMem& sm) {
    int tid = threadIdx.x;
    int sub = tid >> 5, u = tid & 31;

    // gather full e: 32 coalesced 1KB loads, 4 per-thread accumulators
    {
        int hd = tid >> 6, wh = (tid >> 5) & 1, v = tid & 31;
#pragma unroll
        for (int q = 0; q < 4; ++q) {
            float acc = 0.f;
#pragma unroll
            for (int ss = 0; ss < 8; ++ss)
                acc += epart[(((size_t)(n * 4 + q) * 8 + ss) << 8) + tid];
            sm.e[hd][q][wh][v] = acc;
        }
    }
    __syncthreads();

    float acc0[4] = {0.f, 0.f, 0.f, 0.f};   // row sub
    float acc1[4] = {0.f, 0.f, 0.f, 0.f};   // row sub+8
    float acc2[4] = {0.f, 0.f, 0.f, 0.f};   // row sub+16 (sub<2)

#pragma unroll
    for (int hd = 0; hd < 4; ++hd) {
        // ---- adjn for this head into sm.adj ----
        const float* B = Bp + ((size_t)layer * 4 + hd) * 1024;
        float4 bp4 = ((const float4*)B)[tid];
        float lmin = 1e30f, lmax = -1e30f;
        {
            float* a4 = &sm.adj[tid * 4];
#pragma unroll
            for (int c = 0; c < 4; ++c) {
                int p = tid * 4 + c;
                float val = (&bp4.x)[c] + ((p >> 5) == (p & 31) ? 1.f : 0.f);
                a4[c] = val;
                lmin = fminf(lmin, val);
                lmax = fmaxf(lmax, val);
            }
        }
#pragma unroll
        for (int off = 32; off; off >>= 1) {
            lmin = fminf(lmin, __shfl_xor(lmin, off, 64));
            lmax = fmaxf(lmax, __shfl_xor(lmax, off, 64));
        }
        if ((tid & 63) == 0) { sm.wred[tid >> 6] = lmin; sm.wred[4 + (tid >> 6)] = lmax; }
        __syncthreads();
        lmin = fminf(fminf(sm.wred[0], sm.wred[1]), fminf(sm.wred[2], sm.wred[3]));
        lmax = fmaxf(fmaxf(sm.wred[4], sm.wred[5]), fmaxf(sm.wred[6], sm.wred[7]));
        float inv = 1.f / (lmax - lmin);
        for (int p = tid; p < 1024; p += 256) sm.adj[p] = (sm.adj[p] - lmin) * inv;
        __syncthreads();
        if (tid < 32) {
            float ssum = 0.f;
            for (int j = 0; j < 32; ++j) ssum += sm.adj[tid * 32 + ((j + tid) & 31)];
            sm.d12[tid] = rsqrtf(ssum);
        }
        __syncthreads();
        for (int p = tid; p < 1024; p += 256) {
            int i = p >> 5, j = p & 31;
            sm.adj[p] = sm.d12[i] * sm.adj[p] * sm.d12[j];
        }
        __syncthreads();

#pragma unroll
        for (int tout = 0; tout < 4; ++tout) {
            // ---- att[i][j] for q==tout ----
            for (int p = tid; p < 1024; p += 256) {
                int i = p >> 5, j = p & 31;
                float eq[4], mx = -1e30f;
#pragma unroll
                for (int q = 0; q < 4; ++q) {
                    eq[q] = lrelu(sm.e[hd][q][0][i] + sm.e[hd][q][1][j]);
                    mx = fmaxf(mx, eq[q]);
                }
                float ssum = 0.f;
#pragma unroll
                for (int q = 0; q < 4; ++q) { eq[q] = __expf(eq[q] - mx); ssum += eq[q]; }
                sm.att[p] = eq[tout] / ssum;
            }
            __syncthreads();
            // ---- C[j][u] = sum_i att[i][j] * adjn[i][u] ----
            for (int p = tid; p < 1024; p += 256) {
                int j = p >> 5, u2 = p & 31;
                float c = 0.f;
#pragma unroll
                for (int i = 0; i < 32; ++i)
                    c = fmaf(sm.att[i * 32 + j], sm.adj[i * 32 + u2], c);
                sm.C[p] = c;
            }
            __syncthreads();
            // ---- GEMM rows: d = Wh_row . C_col(u), acc += elu(d) ----
            float cc[32];
#pragma unroll
            for (int j = 0; j < 32; ++j) cc[j] = sm.C[j * 32 + u];
            {
                const float* w0 = &sm.Wh[hd][tout][sub][0];
                const float* w1 = &sm.Wh[hd][tout][sub + 8][0];
                float d0 = 0.f, d1 = 0.f;
#pragma unroll
                for (int j = 0; j < 32; ++j) {
                    d0 = fmaf(w0[j], cc[j], d0);
                    d1 = fmaf(w1[j], cc[j], d1);
                }
                acc0[tout] += elu1(d0);
                acc1[tout] += elu1(d1);
                if (sub < 2) {
                    const float* w2 = &sm.Wh[hd][tout][sub + 16][0];
                    float d2 = 0.f;
#pragma unroll
                    for (int j = 0; j < 32; ++j) d2 = fmaf(w2[j], cc[j], d2);
                    acc2[tout] += elu1(d2);
                }
            }
            __syncthreads();    // protect att/C for next tout
        }
    }

    if (layer == 0) {
#pragma unroll
        for (int tout = 0; tout < 4; ++tout) {
            sm.xb[sub][tout][u]     = 0.25f * acc0[tout];
            sm.xb[sub + 8][tout][u] = 0.25f * acc1[tout];
            if (sub < 2) sm.xb[sub + 16][tout][u] = 0.25f * acc2[tout];
        }
    } else {
        size_t mb = (size_t)(n * MM + t * 144 + s * 18);
#pragma unroll
        for (int tout = 0; tout < 4; ++tout) {
            outg[((mb + sub) * 4 + tout) * 32 + u]     = 0.25f * acc0[tout];
            outg[((mb + sub + 8) * 4 + tout) * 32 + u] = 0.25f * acc1[tout];
            if (sub < 2)
                outg[((mb + sub + 16) * 4 + tout) * 32 + u] = 0.25f * acc2[tout];
        }
    }
}

// ---------------------------------------------------------------------------
__global__ __launch_bounds__(256) void fused_kernel(const float* __restrict__ x,
                                                    const float* __restrict__ map_w,
                                                    const float* __restrict__ map_b,
                                                    const float* __restrict__ a_temp,
                                                    const float* __restrict__ Bp,
                                                    float* __restrict__ out,
                                                    float* __restrict__ ws,
                                                    unsigned* __restrict__ cnt) {
    __shared__ SMem sm;
    float* epart0 = ws;              // 32768 floats
    float* epart1 = ws + 32768;      // 32768 floats
    int b = blockIdx.x;
    int n = b >> 5, t = (b >> 3) & 3, s = b & 7;

    phase1(n, t, s, x, map_w, map_b, a_temp, epart0, sm);
    grid_barrier(cnt, NBLK);
    phase23(n, t, s, 0, Bp, epart0, out, sm);
    phase1(n, t, s, nullptr, map_w + 64, map_b + 16, a_temp + 4608, epart1, sm);
    grid_barrier(cnt, 2 * NBLK);
    phase23(n, t, s, 1, Bp, epart1, out, sm);
}

// ---------------------------------------------------------------------------
extern "C" void kernel_launch(void* const* d_in, const int* in_sizes, int n_in,
                              void* d_out, int out_size, void* d_ws, size_t ws_size,
                              hipStream_t stream) {
    const float* x      = (const float*)d_in[0];
    const float* map_w  = (const float*)d_in[1];
    const float* map_b  = (const float*)d_in[2];
    const float* a_temp = (const float*)d_in[3];
    const float* Bp     = (const float*)d_in[4];
    float* out = (float*)d_out;
    float* ws  = (float*)d_ws;

    unsigned* cnt = (unsigned*)((char*)d_ws + (4 << 20));   // far from epart
    hipMemsetAsync(cnt, 0, 64, stream);
    fused_kernel<<<NBLK, 256, 0, stream>>>(x, map_w, map_b, a_temp, Bp, out, ws, cnt);
}

// Round 6
// 152.233 us; speedup vs baseline: 1.4920x; 1.4920x over previous
//
#include <hip/hip_runtime.h>

#define MM 576
#define NBLK 128    // 4n x 4t x 8s; <=256 so all blocks co-resident

__device__ __forceinline__ float lrelu(float x) { return x > 0.f ? x : 0.2f * x; }
__device__ __forceinline__ float elu1(float x)  { return x > 0.f ? x : (__expf(x) - 1.f); }

// Grid barrier: one arrival RMW per block + load-only polling. Only dirty
// data at each barrier is the 128KB epart buffer, so the release fence has
// almost nothing to write back.
__device__ __forceinline__ void grid_barrier(unsigned* cnt, unsigned target) {
    __syncthreads();
    if (threadIdx.x == 0) {
        __threadfence();
        __hip_atomic_fetch_add(cnt, 1u, __ATOMIC_RELAXED, __HIP_MEMORY_SCOPE_AGENT);
        while (__hip_atomic_load(cnt, __ATOMIC_RELAXED, __HIP_MEMORY_SCOPE_AGENT) < target)
            __builtin_amdgcn_s_sleep(2);
        __threadfence();
    }
    __syncthreads();
}

struct SMem {
    float Wh[4][4][18][32];   // [hd][tt][r][v] 36 KB — block-private
    float xb[18][4][32];      // x / inter slice 9 KB — layer boundary
    float e[4][4][2][32];     // [hd][q][which][v] gathered logits, 4 KB
    float adj[1024];          // adjn for current head (phase1: red scratch)
    float att[1024];
    float C[1024];
    float wred[16];
    float d12[32];
};                            // 62656 B

// ---------------------------------------------------------------------------
// Phase 1: block (n,t,s) owns rows m = t*144 + s*18 + [0,18).
// (unchanged from round 5 — verified correct)
// ---------------------------------------------------------------------------
__device__ void phase1(int n, int t, int s,
                       const float* __restrict__ xin,
                       const float* __restrict__ mw_l,
                       const float* __restrict__ mb_l,
                       const float* __restrict__ a_l,
                       float* __restrict__ epart,
                       SMem& sm) {
    int tid = threadIdx.x;
    __syncthreads();    // xb/Wh safe to overwrite; prior phase done
    if (xin) {
        const float4* src = (const float4*)(xin + (size_t)(n * MM + t * 144 + s * 18) * 128);
        float4* dst = (float4*)&sm.xb[0][0][0];
        for (int p = tid; p < 576; p += 256) dst[p] = src[p];
        __syncthreads();
    }
    int sub = tid >> 5, v = tid & 31;
    float ei[4] = {0.f, 0.f, 0.f, 0.f}, ej[4] = {0.f, 0.f, 0.f, 0.f};
    for (int r = sub; r < 18; r += 8) {
        int rr = s * 18 + r;
        int dh = rr / 24, wc = rr % 24;
        float x0 = sm.xb[r][0][v], x1 = sm.xb[r][1][v];
        float x2 = sm.xb[r][2][v], x3 = sm.xb[r][3][v];
#pragma unroll
        for (int hd = 0; hd < 4; ++hd) {
            const float* ab = a_l + hd * 1152 + dh * 192 + wc * 4;
            float4 aiv = *(const float4*)ab;
            float4 ajv = *(const float4*)(ab + 96);
#pragma unroll
            for (int tt = 0; tt < 4; ++tt) {
                float wh = fmaf(x0, mw_l[hd * 16 + tt],
                            fmaf(x1, mw_l[hd * 16 + 4 + tt],
                             fmaf(x2, mw_l[hd * 16 + 8 + tt],
                              fmaf(x3, mw_l[hd * 16 + 12 + tt], mb_l[hd * 4 + tt]))));
                sm.Wh[hd][tt][r][v] = wh;
                float ai = (&aiv.x)[tt], aj = (&ajv.x)[tt];
                ei[hd] = fmaf(wh, ai, ei[hd]);
                ej[hd] = fmaf(wh, aj, ej[hd]);
            }
        }
    }
    float* red = sm.adj;     // [w][hd][wh][v] = 4*4*2*32 scratch
    int w = tid >> 6, half = (tid >> 5) & 1;
#pragma unroll
    for (int hd = 0; hd < 4; ++hd) {
        float eif = ei[hd] + __shfl_xor(ei[hd], 32, 64);
        float ejf = ej[hd] + __shfl_xor(ej[hd], 32, 64);
        red[((w * 4 + hd) * 2 + half) * 32 + v] = half ? ejf : eif;
    }
    __syncthreads();
    {
        int hdx = tid >> 6, whx = (tid >> 5) & 1, vx = tid & 31;
        float e = 0.f;
#pragma unroll
        for (int ww = 0; ww < 4; ++ww)
            e += red[((ww * 4 + hdx) * 2 + whx) * 32 + vx];
        epart[(((size_t)(n * 4 + t) * 8 + s) << 8) + tid] = e;   // tid == hd*64+wh*32+v
    }
}

// ---------------------------------------------------------------------------
// One (hd, TOUT) step of phase 2+3: att -> C -> gemm-accumulate 3 rows.
// TOUT is a template param so accumulators stay statically indexed while the
// enclosing hd loop remains un-unrolled (round-5 spilled from dual unroll).
// ---------------------------------------------------------------------------
template<int TOUT>
__device__ __forceinline__ void att_c_gemm(int hd, int sub, int u, int tid, SMem& sm,
                                           float& a0, float& a1, float& a2) {
    for (int p = tid; p < 1024; p += 256) {
        int i = p >> 5, j = p & 31;
        float eq[4], mx = -1e30f;
#pragma unroll
        for (int q = 0; q < 4; ++q) {
            eq[q] = lrelu(sm.e[hd][q][0][i] + sm.e[hd][q][1][j]);
            mx = fmaxf(mx, eq[q]);
        }
        float ssum = 0.f;
#pragma unroll
        for (int q = 0; q < 4; ++q) { eq[q] = __expf(eq[q] - mx); ssum += eq[q]; }
        sm.att[p] = eq[TOUT] / ssum;
    }
    __syncthreads();
    for (int p = tid; p < 1024; p += 256) {
        int j = p >> 5, u2 = p & 31;
        float c = 0.f;
#pragma unroll
        for (int i = 0; i < 32; ++i)
            c = fmaf(sm.att[i * 32 + j], sm.adj[i * 32 + u2], c);
        sm.C[p] = c;
    }
    __syncthreads();
    float cc[32];
#pragma unroll
    for (int j = 0; j < 32; ++j) cc[j] = sm.C[j * 32 + u];
    const float* w0 = &sm.Wh[hd][TOUT][sub][0];
    const float* w1 = &sm.Wh[hd][TOUT][sub + 8][0];
    float d0 = 0.f, d1 = 0.f;
#pragma unroll
    for (int j = 0; j < 32; ++j) {
        d0 = fmaf(w0[j], cc[j], d0);
        d1 = fmaf(w1[j], cc[j], d1);
    }
    a0 += elu1(d0);
    a1 += elu1(d1);
    if (sub < 2) {
        const float* w2 = &sm.Wh[hd][TOUT][sub + 16][0];
        float d2 = 0.f;
#pragma unroll
        for (int j = 0; j < 32; ++j) d2 = fmaf(w2[j], cc[j], d2);
        a2 += elu1(d2);
    }
    __syncthreads();    // protect att/C before next overwrite
}

// ---------------------------------------------------------------------------
// Phase 2+3 (every block, redundant per n): gather e, then per hd: adjn; per
// (hd,tout): att -> C -> gemm. Layer 0 -> xb (LDS), layer 1 -> global out.
// ---------------------------------------------------------------------------
__device__ void phase23(int n, int t, int s, int layer,
                        const float* __restrict__ Bp,
                        const float* __restrict__ epart,
                        float* __restrict__ outg,
                        SMem& sm) {
    int tid = threadIdx.x;
    int sub = tid >> 5, u = tid & 31;

    {   // gather full e: coalesced 1KB loads
        int hd = tid >> 6, wh = (tid >> 5) & 1, v = tid & 31;
#pragma unroll
        for (int q = 0; q < 4; ++q) {
            float acc = 0.f;
#pragma unroll
            for (int ss = 0; ss < 8; ++ss)
                acc += epart[(((size_t)(n * 4 + q) * 8 + ss) << 8) + tid];
            sm.e[hd][q][wh][v] = acc;
        }
    }
    __syncthreads();

    float a00 = 0.f, a01 = 0.f, a02 = 0.f, a03 = 0.f;   // row sub
    float a10 = 0.f, a11 = 0.f, a12 = 0.f, a13 = 0.f;   // row sub+8
    float a20 = 0.f, a21 = 0.f, a22 = 0.f, a23 = 0.f;   // row sub+16 (sub<2)

#pragma unroll 1
    for (int hd = 0; hd < 4; ++hd) {
        // ---- adjn for this head into sm.adj ----
        const float* B = Bp + ((size_t)layer * 4 + hd) * 1024;
        float4 bp4 = ((const float4*)B)[tid];
        float lmin = 1e30f, lmax = -1e30f;
        {
            float* a4 = &sm.adj[tid * 4];
#pragma unroll
            for (int c = 0; c < 4; ++c) {
                int p = tid * 4 + c;
                float val = (&bp4.x)[c] + ((p >> 5) == (p & 31) ? 1.f : 0.f);
                a4[c] = val;
                lmin = fminf(lmin, val);
                lmax = fmaxf(lmax, val);
            }
        }
#pragma unroll
        for (int off = 32; off; off >>= 1) {
            lmin = fminf(lmin, __shfl_xor(lmin, off, 64));
            lmax = fmaxf(lmax, __shfl_xor(lmax, off, 64));
        }
        if ((tid & 63) == 0) { sm.wred[tid >> 6] = lmin; sm.wred[4 + (tid >> 6)] = lmax; }
        __syncthreads();
        lmin = fminf(fminf(sm.wred[0], sm.wred[1]), fminf(sm.wred[2], sm.wred[3]));
        lmax = fmaxf(fmaxf(sm.wred[4], sm.wred[5]), fmaxf(sm.wred[6], sm.wred[7]));
        float inv = 1.f / (lmax - lmin);
        for (int p = tid; p < 1024; p += 256) sm.adj[p] = (sm.adj[p] - lmin) * inv;
        __syncthreads();
        if (tid < 32) {
            float ssum = 0.f;
            for (int j = 0; j < 32; ++j) ssum += sm.adj[tid * 32 + ((j + tid) & 31)];
            sm.d12[tid] = rsqrtf(ssum);
        }
        __syncthreads();
        for (int p = tid; p < 1024; p += 256) {
            int i = p >> 5, j = p & 31;
            sm.adj[p] = sm.d12[i] * sm.adj[p] * sm.d12[j];
        }
        __syncthreads();

        att_c_gemm<0>(hd, sub, u, tid, sm, a00, a10, a20);
        att_c_gemm<1>(hd, sub, u, tid, sm, a01, a11, a21);
        att_c_gemm<2>(hd, sub, u, tid, sm, a02, a12, a22);
        att_c_gemm<3>(hd, sub, u, tid, sm, a03, a13, a23);
    }

    if (layer == 0) {
        sm.xb[sub][0][u] = 0.25f * a00;  sm.xb[sub][1][u] = 0.25f * a01;
        sm.xb[sub][2][u] = 0.25f * a02;  sm.xb[sub][3][u] = 0.25f * a03;
        sm.xb[sub + 8][0][u] = 0.25f * a10;  sm.xb[sub + 8][1][u] = 0.25f * a11;
        sm.xb[sub + 8][2][u] = 0.25f * a12;  sm.xb[sub + 8][3][u] = 0.25f * a13;
        if (sub < 2) {
            sm.xb[sub + 16][0][u] = 0.25f * a20;  sm.xb[sub + 16][1][u] = 0.25f * a21;
            sm.xb[sub + 16][2][u] = 0.25f * a22;  sm.xb[sub + 16][3][u] = 0.25f * a23;
        }
    } else {
        size_t mb = (size_t)(n * MM + t * 144 + s * 18);
        float* o0 = outg + ((mb + sub) * 4) * 32 + u;
        float* o1 = outg + ((mb + sub + 8) * 4) * 32 + u;
        o0[0] = 0.25f * a00; o0[32] = 0.25f * a01; o0[64] = 0.25f * a02; o0[96] = 0.25f * a03;
        o1[0] = 0.25f * a10; o1[32] = 0.25f * a11; o1[64] = 0.25f * a12; o1[96] = 0.25f * a13;
        if (sub < 2) {
            float* o2 = outg + ((mb + sub + 16) * 4) * 32 + u;
            o2[0] = 0.25f * a20; o2[32] = 0.25f * a21; o2[64] = 0.25f * a22; o2[96] = 0.25f * a23;
        }
    }
}

// ---------------------------------------------------------------------------
__global__ __launch_bounds__(256) void fused_kernel(const float* __restrict__ x,
                                                    const float* __restrict__ map_w,
                                                    const float* __restrict__ map_b,
                                                    const float* __restrict__ a_temp,
                                                    const float* __restrict__ Bp,
                                                    float* __restrict__ out,
                                                    float* __restrict__ ws,
                                                    unsigned* __restrict__ cnt) {
    __shared__ SMem sm;
    float* epart0 = ws;
    float* epart1 = ws + 32768;
    int b = blockIdx.x;
    int n = b >> 5, t = (b >> 3) & 3, s = b & 7;

    phase1(n, t, s, x, map_w, map_b, a_temp, epart0, sm);
    grid_barrier(cnt, NBLK);
    phase23(n, t, s, 0, Bp, epart0, out, sm);
    phase1(n, t, s, nullptr, map_w + 64, map_b + 16, a_temp + 4608, epart1, sm);
    grid_barrier(cnt, 2 * NBLK);
    phase23(n, t, s, 1, Bp, epart1, out, sm);
}

// ---------------------------------------------------------------------------
extern "C" void kernel_launch(void* const* d_in, const int* in_sizes, int n_in,
                              void* d_out, int out_size, void* d_ws, size_t ws_size,
                              hipStream_t stream) {
    const float* x      = (const float*)d_in[0];
    const float* map_w  = (const float*)d_in[1];
    const float* map_b  = (const float*)d_in[2];
    const float* a_temp = (const float*)d_in[3];
    const float* Bp     = (const float*)d_in[4];
    float* out = (float*)d_out;
    float* ws  = (float*)d_ws;

    unsigned* cnt = (unsigned*)((char*)d_ws + (4 << 20));
    hipMemsetAsync(cnt, 0, 64, stream);
    fused_kernel<<<NBLK, 256, 0, stream>>>(x, map_w, map_b, a_temp, Bp, out, ws, cnt);
}

// Round 7
// 94.306 us; speedup vs baseline: 2.4085x; 1.6142x over previous
//
#include <hip/hip_runtime.h>

#define MM 576
#define NBLK 128    // 4n x 4t x 8s; <=256 so all blocks co-resident

__device__ __forceinline__ float lrelu(float x) { return x > 0.f ? x : 0.2f * x; }
__device__ __forceinline__ float elu1(float x)  { return x > 0.f ? x : (__expf(x) - 1.f); }
__device__ __forceinline__ unsigned short f2bf(float f) {   // RNE
    unsigned u = __float_as_uint(f);
    return (unsigned short)((u + 0x7FFFu + ((u >> 16) & 1u)) >> 16);
}

// Agent-scope (device-coherent, L2-bypassing) 4B accesses for the only
// cross-block payload (epart, 1KB/block). Lets the grid barrier skip
// __threadfence's L2 writeback/invalidate entirely.
__device__ __forceinline__ void gstore(float* p, float v) {
    __hip_atomic_store(p, v, __ATOMIC_RELAXED, __HIP_MEMORY_SCOPE_AGENT);
}
__device__ __forceinline__ float gload(const float* p) {
    return __hip_atomic_load(const_cast<float*>(p), __ATOMIC_RELAXED, __HIP_MEMORY_SCOPE_AGENT);
}

// Fence-free grid barrier: each wave drains its own (agent-scope) stores
// with vmcnt(0); __syncthreads orders all waves; leader does one RMW and
// load-only polls. No buffer_wbl2 / buffer_inv anywhere.
__device__ __forceinline__ void grid_barrier(unsigned* cnt, unsigned target) {
    asm volatile("s_waitcnt vmcnt(0)" ::: "memory");
    __syncthreads();
    if (threadIdx.x == 0) {
        __hip_atomic_fetch_add(cnt, 1u, __ATOMIC_RELAXED, __HIP_MEMORY_SCOPE_AGENT);
        while (__hip_atomic_load(cnt, __ATOMIC_RELAXED, __HIP_MEMORY_SCOPE_AGENT) < target)
            __builtin_amdgcn_s_sleep(2);
    }
    __syncthreads();
}

struct SMem {
    unsigned short Whh[4][4][18][32];   // [hd][tt][r][v] bf16, 18 KB
    float xb[18][4][32];                // x / inter slice, 9 KB (layer boundary)
    float e[4][4][2][32];               // [hd][q][which][v] logits, 4 KB
    float adj4[4][1024];                // adjn per head, 16 KB (phase1: red scratch)
    float attC[4][1024];                // per-wave att^T, overwritten by C, 16 KB
    float d12w[4][32];                  // 512 B
};                                      // 65024 B <= 64 KB

// ---------------------------------------------------------------------------
// Phase 1: block (n,t,s) owns rows m = t*144 + s*18 + [0,18).
// Wh -> LDS (bf16); separable logit partials -> epart via agent stores.
// ---------------------------------------------------------------------------
__device__ void phase1(int n, int t, int s,
                       const float* __restrict__ xin,
                       const float* __restrict__ mw_l,
                       const float* __restrict__ mb_l,
                       const float* __restrict__ a_l,
                       float* __restrict__ epart,
                       SMem& sm) {
    int tid = threadIdx.x;
    __syncthreads();    // prior phase done with Whh/xb/adj4
    if (xin) {
        const float4* src = (const float4*)(xin + (size_t)(n * MM + t * 144 + s * 18) * 128);
        float4* dst = (float4*)&sm.xb[0][0][0];
        for (int p = tid; p < 576; p += 256) dst[p] = src[p];
    }
    __syncthreads();
    int sub = tid >> 5, v = tid & 31;
    float ei[4] = {0.f, 0.f, 0.f, 0.f}, ej[4] = {0.f, 0.f, 0.f, 0.f};
    for (int r = sub; r < 18; r += 8) {
        int rr = s * 18 + r;
        int dh = rr / 24, wc = rr % 24;
        float x0 = sm.xb[r][0][v], x1 = sm.xb[r][1][v];
        float x2 = sm.xb[r][2][v], x3 = sm.xb[r][3][v];
#pragma unroll
        for (int hd = 0; hd < 4; ++hd) {
            const float* ab = a_l + hd * 1152 + dh * 192 + wc * 4;
            float4 aiv = *(const float4*)ab;
            float4 ajv = *(const float4*)(ab + 96);
#pragma unroll
            for (int tt = 0; tt < 4; ++tt) {
                float wh = fmaf(x0, mw_l[hd * 16 + tt],
                            fmaf(x1, mw_l[hd * 16 + 4 + tt],
                             fmaf(x2, mw_l[hd * 16 + 8 + tt],
                              fmaf(x3, mw_l[hd * 16 + 12 + tt], mb_l[hd * 4 + tt]))));
                sm.Whh[hd][tt][r][v] = f2bf(wh);
                ei[hd] = fmaf(wh, (&aiv.x)[tt], ei[hd]);
                ej[hd] = fmaf(wh, (&ajv.x)[tt], ej[hd]);
            }
        }
    }
    float* red = &sm.adj4[0][0];        // [w][hd][wh][v] scratch (1024 floats)
    int w = tid >> 6, half = (tid >> 5) & 1;
#pragma unroll
    for (int hd = 0; hd < 4; ++hd) {
        float eif = ei[hd] + __shfl_xor(ei[hd], 32, 64);
        float ejf = ej[hd] + __shfl_xor(ej[hd], 32, 64);
        red[((w * 4 + hd) * 2 + half) * 32 + v] = half ? ejf : eif;
    }
    __syncthreads();
    {
        int hdx = tid >> 6, whx = (tid >> 5) & 1, vx = tid & 31;
        float e = 0.f;
#pragma unroll
        for (int ww = 0; ww < 4; ++ww)
            e += red[((ww * 4 + hdx) * 2 + whx) * 32 + vx];
        gstore(&epart[(((size_t)(n * 4 + t) * 8 + s) << 8) + tid], e);   // tid = hd*64+wh*32+v
    }
}

// ---------------------------------------------------------------------------
// Phase 2+3: SYNC-FREE main loop. Wave w owns tout=w, loops hd 0..3:
//   att^T (transposed by construction, linear LDS store) -> C (registers,
//   written back over att) -> gemm rows with bf16 Wh. All LDS reads are
//   stride-1/float4 or broadcast. Relies on per-wave in-order LDS.
// ---------------------------------------------------------------------------
__device__ void phase23(int n, int t, int s, int layer,
                        const float* __restrict__ Bp,
                        const float* __restrict__ epart,
                        float* __restrict__ outg,
                        SMem& sm) {
    int tid = threadIdx.x;
    int w = tid >> 6;             // wave id == tout
    int lane = tid & 63;
    int u = lane & 31, h = lane >> 5;

    {   // gather e over 8 s-slices (agent loads, all independent)
        int hd = tid >> 6, wh = (tid >> 5) & 1, v = tid & 31;
#pragma unroll
        for (int q = 0; q < 4; ++q) {
            float acc = 0.f;
#pragma unroll
            for (int ss = 0; ss < 8; ++ss)
                acc += gload(&epart[(((size_t)(n * 4 + q) * 8 + ss) << 8) + tid]);
            sm.e[hd][q][wh][v] = acc;
        }
    }

    {   // wave w builds adjn for head w into adj4[w] — wave-private, shfl reductions
        const float* B = Bp + ((size_t)layer * 4 + w) * 1024;
        float val[16];
        float lmin = 1e30f, lmax = -1e30f;
#pragma unroll
        for (int k = 0; k < 16; ++k) {
            int p = lane + 64 * k;
            float vv = B[p] + ((p >> 5) == (p & 31) ? 1.f : 0.f);
            val[k] = vv;
            lmin = fminf(lmin, vv);
            lmax = fmaxf(lmax, vv);
        }
#pragma unroll
        for (int off = 32; off; off >>= 1) {
            lmin = fminf(lmin, __shfl_xor(lmin, off, 64));
            lmax = fmaxf(lmax, __shfl_xor(lmax, off, 64));
        }
        float inv = 1.f / (lmax - lmin);
#pragma unroll
        for (int k = 0; k < 16; ++k) {
            val[k] = (val[k] - lmin) * inv;
            sm.adj4[w][lane + 64 * k] = val[k];
        }
        // row sums: lane = (i, jhalf); rotated reads -> conflict-free
        float rs = 0.f;
        int i_ = lane & 31, h_ = lane >> 5;
#pragma unroll
        for (int jj = 0; jj < 16; ++jj) {
            int j_ = (jj + (h_ ? 16 : 0) + i_) & 31;
            rs += sm.adj4[w][i_ * 32 + j_];
        }
        rs += __shfl_xor(rs, 32, 64);
        if (lane < 32) sm.d12w[w][lane] = rsqrtf(rs);
#pragma unroll
        for (int k = 0; k < 16; ++k) {
            int p = lane + 64 * k;
            sm.adj4[w][p] = val[k] * sm.d12w[w][p >> 5] * sm.d12w[w][p & 31];
        }
    }
    __syncthreads();    // e + all 4 adjn ready for everyone

    float acc[9] = {0.f, 0.f, 0.f, 0.f, 0.f, 0.f, 0.f, 0.f, 0.f};
    float* attC = sm.attC[w];

#pragma unroll 1
    for (int hd = 0; hd < 4; ++hd) {
        // ---- att^T: element (i = p&31, j = p>>5) stored at linear p ----
#pragma unroll
        for (int k = 0; k < 16; ++k) {
            int p = lane + 64 * k;
            int i = p & 31, j = p >> 5;
            float eq0 = lrelu(sm.e[hd][0][0][i] + sm.e[hd][0][1][j]);
            float eq1 = lrelu(sm.e[hd][1][0][i] + sm.e[hd][1][1][j]);
            float eq2 = lrelu(sm.e[hd][2][0][i] + sm.e[hd][2][1][j]);
            float eq3 = lrelu(sm.e[hd][3][0][i] + sm.e[hd][3][1][j]);
            float mx = fmaxf(fmaxf(eq0, eq1), fmaxf(eq2, eq3));
            eq0 = __expf(eq0 - mx); eq1 = __expf(eq1 - mx);
            eq2 = __expf(eq2 - mx); eq3 = __expf(eq3 - mx);
            float invs = __builtin_amdgcn_rcpf(eq0 + eq1 + eq2 + eq3);
            float num = (w & 2) ? ((w & 1) ? eq3 : eq2) : ((w & 1) ? eq1 : eq0);
            attC[p] = num * invs;
        }
        // ---- adj column u into registers (conflict-free: consecutive u) ----
        float av[32];
#pragma unroll
        for (int i = 0; i < 32; ++i) av[i] = sm.adj4[hd][i * 32 + u];
        // ---- C[j][u] = dot(attT row j, av); rows broadcast per half-wave ----
        float cloc[16];
#pragma unroll
        for (int k = 0; k < 16; ++k) {
            int j = h + 2 * k;
            const float4* row = (const float4*)&attC[j * 32];
            float c = 0.f;
#pragma unroll
            for (int q4 = 0; q4 < 8; ++q4) {
                float4 a4 = row[q4];
                c = fmaf(a4.x, av[q4 * 4 + 0], c);
                c = fmaf(a4.y, av[q4 * 4 + 1], c);
                c = fmaf(a4.z, av[q4 * 4 + 2], c);
                c = fmaf(a4.w, av[q4 * 4 + 3], c);
            }
            cloc[k] = c;
        }
#pragma unroll
        for (int k = 0; k < 16; ++k) attC[(h + 2 * k) * 32 + u] = cloc[k];
        // ---- gemm: rows r = h*9 .. h*9+8, bf16 Wh broadcast reads ----
        float cc[32];
#pragma unroll
        for (int j = 0; j < 32; ++j) cc[j] = attC[j * 32 + u];
#pragma unroll
        for (int r9 = 0; r9 < 9; ++r9) {
            int r = h * 9 + r9;
            const unsigned* wrow = (const unsigned*)&sm.Whh[hd][w][r][0];
            float d = 0.f;
#pragma unroll
            for (int j2 = 0; j2 < 16; ++j2) {
                unsigned pk = wrow[j2];
                d = fmaf(__uint_as_float(pk << 16),          cc[2 * j2],     d);
                d = fmaf(__uint_as_float(pk & 0xFFFF0000u),  cc[2 * j2 + 1], d);
            }
            acc[r9] += elu1(d);
        }
    }

    if (layer == 0) {
#pragma unroll
        for (int r9 = 0; r9 < 9; ++r9)
            sm.xb[h * 9 + r9][w][u] = 0.25f * acc[r9];
    } else {
        size_t mb = (size_t)(n * MM + t * 144 + s * 18);
#pragma unroll
        for (int r9 = 0; r9 < 9; ++r9)
            outg[((mb + h * 9 + r9) * 4 + w) * 32 + u] = 0.25f * acc[r9];
    }
}

// ---------------------------------------------------------------------------
__global__ __launch_bounds__(256) void fused_kernel(const float* __restrict__ x,
                                                    const float* __restrict__ map_w,
                                                    const float* __restrict__ map_b,
                                                    const float* __restrict__ a_temp,
                                                    const float* __restrict__ Bp,
                                                    float* __restrict__ out,
                                                    float* __restrict__ ws,
                                                    unsigned* __restrict__ cnt) {
    __shared__ SMem sm;
    float* epart0 = ws;
    float* epart1 = ws + 32768;
    int b = blockIdx.x;
    int n = b >> 5, t = (b >> 3) & 3, s = b & 7;

    phase1(n, t, s, x, map_w, map_b, a_temp, epart0, sm);
    grid_barrier(cnt, NBLK);
    phase23(n, t, s, 0, Bp, epart0, out, sm);
    phase1(n, t, s, nullptr, map_w + 64, map_b + 16, a_temp + 4608, epart1, sm);
    grid_barrier(cnt, 2 * NBLK);
    phase23(n, t, s, 1, Bp, epart1, out, sm);
}

// ---------------------------------------------------------------------------
extern "C" void kernel_launch(void* const* d_in, const int* in_sizes, int n_in,
                              void* d_out, int out_size, void* d_ws, size_t ws_size,
                              hipStream_t stream) {
    const float* x      = (const float*)d_in[0];
    const float* map_w  = (const float*)d_in[1];
    const float* map_b  = (const float*)d_in[2];
    const float* a_temp = (const float*)d_in[3];
    const float* Bp     = (const float*)d_in[4];
    float* out = (float*)d_out;
    float* ws  = (float*)d_ws;

    unsigned* cnt = (unsigned*)((char*)d_ws + (4 << 20));
    hipMemsetAsync(cnt, 0, 64, stream);
    fused_kernel<<<NBLK, 256, 0, stream>>>(x, map_w, map_b, a_temp, Bp, out, ws, cnt);
}

// Round 8
// 65.977 us; speedup vs baseline: 3.4427x; 1.4294x over previous
//
#include <hip/hip_runtime.h>

#define MM 576
#define NBLK 128    // 4n x 4t x 8s; <=256 so all blocks co-resident
#define NTHR 512    // 8 waves: (g, tout) -> hd pair 2g..2g+1, output t' = tout

__device__ __forceinline__ float lrelu(float x) { return x > 0.f ? x : 0.2f * x; }
__device__ __forceinline__ float elu1(float x)  { return x > 0.f ? x : (__expf(x) - 1.f); }
__device__ __forceinline__ unsigned short f2bf(float f) {   // RNE
    unsigned u = __float_as_uint(f);
    return (unsigned short)((u + 0x7FFFu + ((u >> 16) & 1u)) >> 16);
}
__device__ __forceinline__ float bf2f(unsigned short h) {
    return __uint_as_float(((unsigned)h) << 16);
}

// Agent-scope (device-coherent) 4B accesses for the only cross-block payload
// (epart). Grid barrier then needs no L2 writeback/invalidate.
__device__ __forceinline__ void gstore(float* p, float v) {
    __hip_atomic_store(p, v, __ATOMIC_RELAXED, __HIP_MEMORY_SCOPE_AGENT);
}
__device__ __forceinline__ float gload(const float* p) {
    return __hip_atomic_load(const_cast<float*>(p), __ATOMIC_RELAXED, __HIP_MEMORY_SCOPE_AGENT);
}

// Fence-free grid barrier (validated round 7).
__device__ __forceinline__ void grid_barrier(unsigned* cnt, unsigned target) {
    asm volatile("s_waitcnt vmcnt(0)" ::: "memory");
    __syncthreads();
    if (threadIdx.x == 0) {
        __hip_atomic_fetch_add(cnt, 1u, __ATOMIC_RELAXED, __HIP_MEMORY_SCOPE_AGENT);
        while (__hip_atomic_load(cnt, __ATOMIC_RELAXED, __HIP_MEMORY_SCOPE_AGENT) < target)
            __builtin_amdgcn_s_sleep(2);
    }
    __syncthreads();
}

struct SMem {
    unsigned short Whh[4][4][18][32];   // [hd][tt][r][v] bf16, 18432 B
    unsigned short adjh[4][1024];       // adjn per head, bf16, 8192 B
    float e[4][4][2][32];               // [hd][q][which][v], 4096 B
    // unionf, phase-disjoint lifetimes:
    //   [0,2304)      xb: x / inter slice [18][4][32] (layer boundary)
    //   w*1024..+1024 attC[w]: per-wave adj-scratch -> att^T -> C  (w=0..7)
    //   [4096,6144)   phase1 red scratch [8][4][2][32]
    //   (4+tout)*1024 g=1 partial accumulators (9*64 floats)
    float unionf[8192];                 // 32768 B
    float d12w[4][32];                  // 512 B
};                                      // 64000 B

// ---------------------------------------------------------------------------
// Phase 1: block (n,t,s) owns rows m = t*144 + s*18 + [0,18).
// Wh -> LDS (bf16); separable logit partials -> epart (agent stores).
// ---------------------------------------------------------------------------
__device__ void phase1(int n, int t, int s,
                       const float* __restrict__ xin,
                       const float* __restrict__ mw_l,
                       const float* __restrict__ mb_l,
                       const float* __restrict__ a_l,
                       float* __restrict__ epart,
                       SMem& sm) {
    int tid = threadIdx.x;
    __syncthreads();    // prior phase done with union/Whh
    float* xb = sm.unionf;
    if (xin) {
        const float4* src = (const float4*)(xin + (size_t)(n * MM + t * 144 + s * 18) * 128);
        float4* dst = (float4*)xb;
        for (int p = tid; p < 576; p += NTHR) dst[p] = src[p];
    }
    __syncthreads();
    int sub = tid >> 5, v = tid & 31;   // sub 0..15
    float ei[4] = {0.f, 0.f, 0.f, 0.f}, ej[4] = {0.f, 0.f, 0.f, 0.f};
    for (int r = sub; r < 18; r += 16) {
        int rr = s * 18 + r;
        int dh = rr / 24, wc = rr % 24;
        float x0 = xb[r * 128 + v],      x1 = xb[r * 128 + 32 + v];
        float x2 = xb[r * 128 + 64 + v], x3 = xb[r * 128 + 96 + v];
#pragma unroll
        for (int hd = 0; hd < 4; ++hd) {
            const float* ab = a_l + hd * 1152 + dh * 192 + wc * 4;
            float4 aiv = *(const float4*)ab;
            float4 ajv = *(const float4*)(ab + 96);
#pragma unroll
            for (int tt = 0; tt < 4; ++tt) {
                float wh = fmaf(x0, mw_l[hd * 16 + tt],
                            fmaf(x1, mw_l[hd * 16 + 4 + tt],
                             fmaf(x2, mw_l[hd * 16 + 8 + tt],
                              fmaf(x3, mw_l[hd * 16 + 12 + tt], mb_l[hd * 4 + tt]))));
                sm.Whh[hd][tt][r][v] = f2bf(wh);
                ei[hd] = fmaf(wh, (&aiv.x)[tt], ei[hd]);
                ej[hd] = fmaf(wh, (&ajv.x)[tt], ej[hd]);
            }
        }
    }
    float* red = sm.unionf + 4096;      // [wave8][hd4][wh2][v32]
    int wv = tid >> 6, half = (tid >> 5) & 1;
#pragma unroll
    for (int hd = 0; hd < 4; ++hd) {
        float eif = ei[hd] + __shfl_xor(ei[hd], 32, 64);
        float ejf = ej[hd] + __shfl_xor(ej[hd], 32, 64);
        red[((wv * 4 + hd) * 2 + half) * 32 + v] = half ? ejf : eif;
    }
    __syncthreads();
    if (tid < 256) {        // tid == hd*64 + wh*32 + v
        int hdx = tid >> 6, whx = (tid >> 5) & 1, vx = tid & 31;
        float e = 0.f;
#pragma unroll
        for (int ww = 0; ww < 8; ++ww)
            e += red[((ww * 4 + hdx) * 2 + whx) * 32 + vx];
        gstore(&epart[(((size_t)(n * 4 + t) * 8 + s) << 8) + tid], e);
    }
}

// ---------------------------------------------------------------------------
// Phase 2+3: 8 waves. Wave (g,tout) computes hd in {2g, 2g+1}: att^T (linear
// store) -> C (in place) -> gemm 18 bf16 Wh rows (b128 reads). Partials from
// g=1 summed into g=0 via LDS. Layer 0 -> xb, layer 1 -> global out.
// ---------------------------------------------------------------------------
__device__ void phase23(int n, int t, int s, int layer,
                        const float* __restrict__ Bp,
                        const float* __restrict__ epart,
                        float* __restrict__ outg,
                        SMem& sm) {
    int tid = threadIdx.x;
    int w = tid >> 6, lane = tid & 63;
    int g = w >> 2, tout = w & 3;
    int u = lane & 31, h = lane >> 5;
    float* attC = sm.unionf + w * 1024;

    {   // gather e over 8 s-slices: 512 threads cover (hd, qh, wh, v) x 2 q
        int hd = tid >> 7, rem = tid & 127;
        int qh = rem >> 6, wh = (rem >> 5) & 1, v = rem & 31;
        int le = hd * 64 + wh * 32 + v;
#pragma unroll
        for (int qq = 0; qq < 2; ++qq) {
            int q = qh * 2 + qq;
            float acc = 0.f;
#pragma unroll
            for (int ss = 0; ss < 8; ++ss)
                acc += gload(&epart[(((size_t)(n * 4 + q) * 8 + ss) << 8) + le]);
            sm.e[hd][q][wh][v] = acc;
        }
    }

    if (g == 0) {   // waves 0-3: build adjn for head tout (fp32 scratch in attC)
        const float* B = Bp + ((size_t)layer * 4 + tout) * 1024;
        float val[16];
        float lmin = 1e30f, lmax = -1e30f;
#pragma unroll
        for (int k = 0; k < 16; ++k) {
            int p = lane + 64 * k;
            float vv = B[p] + ((p >> 5) == (p & 31) ? 1.f : 0.f);
            val[k] = vv;
            lmin = fminf(lmin, vv);
            lmax = fmaxf(lmax, vv);
        }
#pragma unroll
        for (int off = 32; off; off >>= 1) {
            lmin = fminf(lmin, __shfl_xor(lmin, off, 64));
            lmax = fmaxf(lmax, __shfl_xor(lmax, off, 64));
        }
        float inv = 1.f / (lmax - lmin);
#pragma unroll
        for (int k = 0; k < 16; ++k) {
            val[k] = (val[k] - lmin) * inv;
            attC[lane + 64 * k] = val[k];
        }
        float rs = 0.f;     // row-sum of row u, rotated: conflict-free
#pragma unroll
        for (int jj = 0; jj < 16; ++jj) {
            int j_ = (jj + (h ? 16 : 0) + u) & 31;
            rs += attC[u * 32 + j_];
        }
        rs += __shfl_xor(rs, 32, 64);
        if (lane < 32) sm.d12w[tout][lane] = rsqrtf(rs);
#pragma unroll
        for (int k = 0; k < 16; ++k) {
            int p = lane + 64 * k;
            sm.adjh[tout][p] = f2bf(val[k] * sm.d12w[tout][p >> 5] * sm.d12w[tout][p & 31]);
        }
    }
    __syncthreads();    // e + all adjn ready

    float acc[9] = {0.f, 0.f, 0.f, 0.f, 0.f, 0.f, 0.f, 0.f, 0.f};

#pragma unroll 1
    for (int ii = 0; ii < 2; ++ii) {
        int hd = g * 2 + ii;
        // ---- att^T[j][i] at attC[j*32+i]; lane p=lane+64k: j=2k+h, i=u ----
        float ei0 = sm.e[hd][0][0][u], ei1 = sm.e[hd][1][0][u];
        float ei2 = sm.e[hd][2][0][u], ei3 = sm.e[hd][3][0][u];
#pragma unroll
        for (int k = 0; k < 16; ++k) {
            int j = 2 * k + h;
            float eq0 = lrelu(ei0 + sm.e[hd][0][1][j]);
            float eq1 = lrelu(ei1 + sm.e[hd][1][1][j]);
            float eq2 = lrelu(ei2 + sm.e[hd][2][1][j]);
            float eq3 = lrelu(ei3 + sm.e[hd][3][1][j]);
            float mx = fmaxf(fmaxf(eq0, eq1), fmaxf(eq2, eq3));
            eq0 = __expf(eq0 - mx); eq1 = __expf(eq1 - mx);
            eq2 = __expf(eq2 - mx); eq3 = __expf(eq3 - mx);
            float invs = __builtin_amdgcn_rcpf(eq0 + eq1 + eq2 + eq3);
            float num = (tout & 2) ? ((tout & 1) ? eq3 : eq2) : ((tout & 1) ? eq1 : eq0);
            attC[j * 32 + u] = num * invs;
        }
        // ---- adj column u (bf16, coalesced) ----
        float av[32];
#pragma unroll
        for (int i = 0; i < 32; ++i) av[i] = bf2f(sm.adjh[hd][i * 32 + u]);
        // ---- C[j][u] = dot(attT row j, av); rows broadcast per half ----
        float cloc[16];
#pragma unroll
        for (int k = 0; k < 16; ++k) {
            const float4* row = (const float4*)&attC[(h + 2 * k) * 32];
            float c = 0.f;
#pragma unroll
            for (int q4 = 0; q4 < 8; ++q4) {
                float4 a4 = row[q4];
                c = fmaf(a4.x, av[q4 * 4 + 0], c);
                c = fmaf(a4.y, av[q4 * 4 + 1], c);
                c = fmaf(a4.z, av[q4 * 4 + 2], c);
                c = fmaf(a4.w, av[q4 * 4 + 3], c);
            }
            cloc[k] = c;
        }
#pragma unroll
        for (int k = 0; k < 16; ++k) attC[(h + 2 * k) * 32 + u] = cloc[k];
        // ---- gemm: rows r = h*9..h*9+8; Wh rows as b128 (16 bf16/read) ----
        float cc[32];
#pragma unroll
        for (int j = 0; j < 32; ++j) cc[j] = attC[j * 32 + u];
#pragma unroll
        for (int r9 = 0; r9 < 9; ++r9) {
            int r = h * 9 + r9;
            const uint4* wr = (const uint4*)&sm.Whh[hd][tout][r][0];
            float d = 0.f;
#pragma unroll
            for (int q4 = 0; q4 < 4; ++q4) {
                uint4 pk = wr[q4];
                d = fmaf(__uint_as_float(pk.x << 16),         cc[8 * q4 + 0], d);
                d = fmaf(__uint_as_float(pk.x & 0xFFFF0000u), cc[8 * q4 + 1], d);
                d = fmaf(__uint_as_float(pk.y << 16),         cc[8 * q4 + 2], d);
                d = fmaf(__uint_as_float(pk.y & 0xFFFF0000u), cc[8 * q4 + 3], d);
                d = fmaf(__uint_as_float(pk.z << 16),         cc[8 * q4 + 4], d);
                d = fmaf(__uint_as_float(pk.z & 0xFFFF0000u), cc[8 * q4 + 5], d);
                d = fmaf(__uint_as_float(pk.w << 16),         cc[8 * q4 + 6], d);
                d = fmaf(__uint_as_float(pk.w & 0xFFFF0000u), cc[8 * q4 + 7], d);
            }
            acc[r9] += elu1(d);
        }
    }

    if (g == 1) {   // publish partials in own attC area (w = 4+tout)
#pragma unroll
        for (int k = 0; k < 9; ++k) attC[k * 64 + lane] = acc[k];
    }
    __syncthreads();
    if (g == 0) {
        const float* part = sm.unionf + (4 + tout) * 1024;
#pragma unroll
        for (int k = 0; k < 9; ++k) acc[k] += part[k * 64 + lane];
        if (layer == 0) {
            float* xb = sm.unionf;
#pragma unroll
            for (int k = 0; k < 9; ++k)
                xb[(h * 9 + k) * 128 + tout * 32 + u] = 0.25f * acc[k];
        } else {
            size_t mb = (size_t)(n * MM + t * 144 + s * 18);
#pragma unroll
            for (int k = 0; k < 9; ++k)
                outg[((mb + h * 9 + k) * 4 + tout) * 32 + u] = 0.25f * acc[k];
        }
    }
}

// ---------------------------------------------------------------------------
__global__ __launch_bounds__(NTHR) void fused_kernel(const float* __restrict__ x,
                                                     const float* __restrict__ map_w,
                                                     const float* __restrict__ map_b,
                                                     const float* __restrict__ a_temp,
                                                     const float* __restrict__ Bp,
                                                     float* __restrict__ out,
                                                     float* __restrict__ ws,
                                                     unsigned* __restrict__ cnt) {
    __shared__ SMem sm;
    float* epart0 = ws;
    float* epart1 = ws + 32768;
    int b = blockIdx.x;
    int n = b >> 5, t = (b >> 3) & 3, s = b & 7;

    phase1(n, t, s, x, map_w, map_b, a_temp, epart0, sm);
    grid_barrier(cnt, NBLK);
    phase23(n, t, s, 0, Bp, epart0, out, sm);
    phase1(n, t, s, nullptr, map_w + 64, map_b + 16, a_temp + 4608, epart1, sm);
    grid_barrier(cnt, 2 * NBLK);
    phase23(n, t, s, 1, Bp, epart1, out, sm);
}

// ---------------------------------------------------------------------------
extern "C" void kernel_launch(void* const* d_in, const int* in_sizes, int n_in,
                              void* d_out, int out_size, void* d_ws, size_t ws_size,
                              hipStream_t stream) {
    const float* x      = (const float*)d_in[0];
    const float* map_w  = (const float*)d_in[1];
    const float* map_b  = (const float*)d_in[2];
    const float* a_temp = (const float*)d_in[3];
    const float* Bp     = (const float*)d_in[4];
    float* out = (float*)d_out;
    float* ws  = (float*)d_ws;

    unsigned* cnt = (unsigned*)((char*)d_ws + (4 << 20));
    hipMemsetAsync(cnt, 0, 64, stream);
    fused_kernel<<<NBLK, NTHR, 0, stream>>>(x, map_w, map_b, a_temp, Bp, out, ws, cnt);
}